// Round 1
// baseline (222.284 us; speedup 1.0000x reference)
//
#include <hip/hip_runtime.h>
#include <hip/hip_bf16.h>

#define INF 128
#define OUTF 64
#define ALPHA 0.2f
#define EPSV 1e-6f

typedef __bf16 bf16x8 __attribute__((ext_vector_type(8)));
typedef float  f32x4  __attribute__((ext_vector_type(4)));

// ---------------------------------------------------------------------------
// k_fc_hist (fat kernel): heterogeneous block roles, interleaved so both are
// co-resident: blockIdx%3==0 -> FC role (MFMA), else -> histogram role
// (atomic deg count). The two are fully independent; hist's atomic latency
// hides under FC's MFMA + global traffic.
//
// FC role: Wh = h @ Wfc^T via 16x16x32 bf16 MFMA, 3-term bf16 split.
// Stores Whb in INTERLEAVED bf16 layout Whb[n][b][64] (256B per node).
// s1/s2 now INTERLEAVED [n][b] (float2 per node) for 8B scatter gathers.
// ---------------------------------------------------------------------------
__global__ __launch_bounds__(256, 2)
void k_fc_hist(const float* __restrict__ h, const float* __restrict__ Wfc,
               const float* __restrict__ Wattn, __hip_bfloat16* __restrict__ Whb,
               float* __restrict__ s1, float* __restrict__ s2,
               const int* __restrict__ e_dst, int* __restrict__ deg,
               int BN, int N, int E, int nhist)
{
    int blk = blockIdx.x;
    int k = blk / 3;
    int r = blk - 3 * k;

    if (r != 0) {
        // ---- histogram role ----
        int histid = 2 * k + (r - 1);
        if (histid < nhist) {
            int e = histid * 256 + threadIdx.x;
            if (e < E) {
                int d = e_dst[e];
                d = min(max(d, 0), N - 1);
                atomicAdd(deg + d, 1);
            }
        }
        return;
    }

    // ---- FC role (fcid = k) ----
    int lane = threadIdx.x & 63;
    int wv   = k * 4 + (threadIdx.x >> 6);
    int base = wv * 16;
    if (base >= BN) return;
    int q = lane & 15, quad = lane >> 4;

    bf16x8 bhi[16], blo[16];
#pragma unroll
    for (int kb = 0; kb < 4; ++kb) {
#pragma unroll
        for (int t = 0; t < 4; ++t) {
            const float* wp = Wfc + (size_t)(t * 16 + q) * INF + kb * 32 + quad * 8;
            float4 w0 = *(const float4*)wp;
            float4 w1 = *(const float4*)(wp + 4);
            float wv8[8] = {w0.x, w0.y, w0.z, w0.w, w1.x, w1.y, w1.z, w1.w};
            bf16x8 hi8, lo8;
#pragma unroll
            for (int j = 0; j < 8; ++j) {
                hi8[j] = (__bf16)wv8[j];
                lo8[j] = (__bf16)(wv8[j] - (float)hi8[j]);
            }
            bhi[kb * 4 + t] = hi8;
            blo[kb * 4 + t] = lo8;
        }
    }

    f32x4 acc[4];
#pragma unroll
    for (int t = 0; t < 4; ++t) acc[t] = (f32x4){0.f, 0.f, 0.f, 0.f};

    const float* hrow = h + (size_t)(base + q) * INF + quad * 8;
#pragma unroll
    for (int kb = 0; kb < 4; ++kb) {
        float4 h0 = *(const float4*)(hrow + kb * 32);
        float4 h1 = *(const float4*)(hrow + kb * 32 + 4);
        float hv8[8] = {h0.x, h0.y, h0.z, h0.w, h1.x, h1.y, h1.z, h1.w};
        bf16x8 ahi, alo;
#pragma unroll
        for (int j = 0; j < 8; ++j) {
            ahi[j] = (__bf16)hv8[j];
            alo[j] = (__bf16)(hv8[j] - (float)ahi[j]);
        }
#pragma unroll
        for (int t = 0; t < 4; ++t) {
            acc[t] = __builtin_amdgcn_mfma_f32_16x16x32_bf16(ahi, bhi[kb * 4 + t], acc[t], 0, 0, 0);
            acc[t] = __builtin_amdgcn_mfma_f32_16x16x32_bf16(ahi, blo[kb * 4 + t], acc[t], 0, 0, 0);
            acc[t] = __builtin_amdgcn_mfma_f32_16x16x32_bf16(alo, bhi[kb * 4 + t], acc[t], 0, 0, 0);
        }
    }

#pragma unroll
    for (int rr4 = 0; rr4 < 4; ++rr4) {
        int rr = base + quad * 4 + rr4;
        int b = (rr >= N) ? 1 : 0;
        int n = rr - b * N;
        __hip_bfloat16* dst = Whb + (size_t)n * 128 + b * 64 + q;
#pragma unroll
        for (int t = 0; t < 4; ++t) dst[t * 16] = __float2bfloat16(acc[t][rr4]);
    }

    float aS[4], aD[4];
#pragma unroll
    for (int t = 0; t < 4; ++t) {
        aS[t] = Wattn[t * 16 + q];
        aD[t] = Wattn[OUTF + t * 16 + q];
    }
    float t1[4], t2[4];
#pragma unroll
    for (int rr4 = 0; rr4 < 4; ++rr4) {
        t1[rr4] = acc[0][rr4] * aS[0] + acc[1][rr4] * aS[1] + acc[2][rr4] * aS[2] + acc[3][rr4] * aS[3];
        t2[rr4] = acc[0][rr4] * aD[0] + acc[1][rr4] * aD[1] + acc[2][rr4] * aD[2] + acc[3][rr4] * aD[3];
    }
#pragma unroll
    for (int off = 1; off <= 8; off <<= 1) {
#pragma unroll
        for (int rr4 = 0; rr4 < 4; ++rr4) {
            t1[rr4] += __shfl_xor(t1[rr4], off, 64);
            t2[rr4] += __shfl_xor(t2[rr4], off, 64);
        }
    }
    if (q == 0) {
#pragma unroll
        for (int rr4 = 0; rr4 < 4; ++rr4) {
            int rr = base + quad * 4 + rr4;
            int b = (rr >= N) ? 1 : 0;
            int n = rr - b * N;
            s1[2 * n + b] = t1[rr4];   // interleaved [n][b]
            s2[2 * n + b] = t2[rr4];
        }
    }
}

// ---------------------------------------------------------------------------
// k_scan (single kernel, replaces scan_blk+scan_fin): each block redundantly
// computes its own exclusive prefix by summing deg[0..start) (L2-resident,
// 200KB), then scans its 2048 elements and writes rowptr AND cursor (the
// scatter kernel's atomic slot counters). rowptr[N] = E (every edge is
// clamped into range, so the grand total is exactly E).
// ---------------------------------------------------------------------------
__global__ __launch_bounds__(256)
void k_scan(const int* __restrict__ deg, int* __restrict__ rowptr,
            int* __restrict__ cursor, int N, int E)
{
    int t = threadIdx.x, lane = t & 63, wave = t >> 6;
    __shared__ int pre_ws[4];
    __shared__ int wsum[4];

    // stage 1: sum of all deg before this block's region
    int myStart = blockIdx.x * 2048;
    int s = 0;
    for (int i0 = t * 8; i0 < myStart; i0 += 2048) {
        int4 v0 = *(const int4*)(deg + i0);
        int4 v1 = *(const int4*)(deg + i0 + 4);
        s += v0.x + v0.y + v0.z + v0.w + v1.x + v1.y + v1.z + v1.w;
    }
#pragma unroll
    for (int off = 32; off >= 1; off >>= 1) s += __shfl_xor(s, off, 64);
    if (lane == 0) pre_ws[wave] = s;
    __syncthreads();
    int pre = pre_ws[0] + pre_ws[1] + pre_ws[2] + pre_ws[3];

    // stage 2: local scan of this block's 2048 elements
    int base = myStart + t * 8;
    int vals[8]; int sl = 0;
#pragma unroll
    for (int j = 0; j < 8; ++j) {
        int i = base + j;
        vals[j] = (i < N) ? deg[i] : 0;
        sl += vals[j];
    }
    int inc = sl;
#pragma unroll
    for (int off = 1; off < 64; off <<= 1) {
        int u = __shfl_up(inc, off, 64);
        if (lane >= off) inc += u;
    }
    if (lane == 63) wsum[wave] = inc;
    __syncthreads();

    int woff = 0;
#pragma unroll
    for (int w = 0; w < 4; ++w) if (w < wave) woff += wsum[w];
    int running = pre + woff + (inc - sl);
#pragma unroll
    for (int j = 0; j < 8; ++j) {
        int i = base + j;
        if (i < N) { rowptr[i] = running; cursor[i] = running; }
        running += vals[j];
    }
    if (blockIdx.x == 0 && t == 0) rowptr[N] = E;
}

// ---------------------------------------------------------------------------
// Scatter v3: slot via atomicAdd on cursor (no rank[] array -> -6.4MB traffic,
// same total atomic count as before, just moved from k_hist here).
// s1/s2 interleaved [n][b]: one float2 gather per endpoint (2x8B vs 4x4B).
// One 8B record per edge: (src:u32, x0:bf16 | x1:bf16<<16).
// ---------------------------------------------------------------------------
__global__ __launch_bounds__(256)
void k_scatter(const int* __restrict__ e_src, const int* __restrict__ e_dst,
               const float* __restrict__ s1, const float* __restrict__ s2,
               int* __restrict__ cursor, uint2* __restrict__ rec, int E, int N)
{
    int e = blockIdx.x * 256 + threadIdx.x;
    if (e >= E) return;
    int d = e_dst[e];
    int s = e_src[e];
    d = min(max(d, 0), N - 1);
    s = min(max(s, 0), N - 1);
    int p = atomicAdd(cursor + d, 1);
    float2 vs = ((const float2*)s1)[s];   // (batch0, batch1) of s1 at src
    float2 vd = ((const float2*)s2)[d];   // (batch0, batch1) of s2 at dst
    float e0 = vs.x + vd.x;
    float e1 = vs.y + vd.y;
    e0 = e0 > 0.f ? e0 : ALPHA * e0;
    e1 = e1 > 0.f ? e1 : ALPHA * e1;
    float x0 = __expf(e0);
    float x1 = __expf(e1);
    __hip_bfloat16 b0 = __float2bfloat16(x0);
    __hip_bfloat16 b1 = __float2bfloat16(x1);
    unsigned u0 = *(unsigned short*)&b0;
    unsigned u1 = *(unsigned short*)&b1;
    rec[p] = make_uint2((unsigned)s, u0 | (u1 << 16));
}

// ---------------------------------------------------------------------------
// k_gather (bf16 Whb, 8B rec): one wave per dst. Lane = (g = edge slot 0..3,
// q = 0..15): q<8 -> batch0 features 8q.., q>=8 -> batch1. 8 edges/iter via
// 2 independent slots. Reduce over g with shfl_xor(16,32); g==0 lanes store.
// ---------------------------------------------------------------------------
__global__ __launch_bounds__(256)
void k_gather(const int* __restrict__ rowptr, const uint2* __restrict__ rec,
              const unsigned int* __restrict__ Whb, float* __restrict__ out, int N)
{
    int lane = threadIdx.x & 63;
    int d = blockIdx.x * 4 + (threadIdx.x >> 6);
    if (d >= N) return;
    int g = lane >> 4, q = lane & 15;
    int b = q >> 3;                 // batch this lane handles

    int beg = rowptr[d];
    int end = rowptr[d + 1];
    const uint4* W = (const uint4*)Whb;   // 16 uint4 per node: [b0 x8][b1 x8]

    float a[8];
#pragma unroll
    for (int j = 0; j < 8; ++j) a[j] = 0.f;
    float nacc = 0.f;

    for (int i = beg; i < end; i += 8) {
        int e0 = i + g;
        int e1 = i + 4 + g;
        int ec0 = min(e0, end - 1);
        int ec1 = min(e1, end - 1);
        uint2 r0 = rec[ec0];
        uint2 r1 = rec[ec1];
        int s0 = (int)r0.x;
        int s1v = (int)r1.x;
        uint4 w0 = W[(size_t)s0 * 16 + q];
        uint4 w1 = W[(size_t)s1v * 16 + q];
        float x0 = (e0 < end) ? __uint_as_float(b ? (r0.y & 0xffff0000u) : (r0.y << 16)) : 0.f;
        float x1 = (e1 < end) ? __uint_as_float(b ? (r1.y & 0xffff0000u) : (r1.y << 16)) : 0.f;

        unsigned int u;
        u = w0.x; a[0] += x0 * __uint_as_float(u << 16); a[1] += x0 * __uint_as_float(u & 0xffff0000u);
        u = w0.y; a[2] += x0 * __uint_as_float(u << 16); a[3] += x0 * __uint_as_float(u & 0xffff0000u);
        u = w0.z; a[4] += x0 * __uint_as_float(u << 16); a[5] += x0 * __uint_as_float(u & 0xffff0000u);
        u = w0.w; a[6] += x0 * __uint_as_float(u << 16); a[7] += x0 * __uint_as_float(u & 0xffff0000u);
        u = w1.x; a[0] += x1 * __uint_as_float(u << 16); a[1] += x1 * __uint_as_float(u & 0xffff0000u);
        u = w1.y; a[2] += x1 * __uint_as_float(u << 16); a[3] += x1 * __uint_as_float(u & 0xffff0000u);
        u = w1.z; a[4] += x1 * __uint_as_float(u << 16); a[5] += x1 * __uint_as_float(u & 0xffff0000u);
        u = w1.w; a[6] += x1 * __uint_as_float(u << 16); a[7] += x1 * __uint_as_float(u & 0xffff0000u);
        nacc += x0 + x1;
    }

#pragma unroll
    for (int off = 16; off <= 32; off <<= 1) {
#pragma unroll
        for (int j = 0; j < 8; ++j) a[j] += __shfl_xor(a[j], off, 64);
        nacc += __shfl_xor(nacc, off, 64);
    }

    if (g == 0) {
        float inv = 1.f / (nacc + EPSV);
        float v[8];
#pragma unroll
        for (int j = 0; j < 8; ++j) {
            v[j] = a[j] * inv;
            v[j] = v[j] > 0.f ? v[j] : expm1f(v[j]);
        }
        size_t rowbase = ((size_t)b * N + d) * 16 + (size_t)(q & 7) * 2;
        ((float4*)out)[rowbase]     = make_float4(v[0], v[1], v[2], v[3]);
        ((float4*)out)[rowbase + 1] = make_float4(v[4], v[5], v[6], v[7]);
    }
}

extern "C" void kernel_launch(void* const* d_in, const int* in_sizes, int n_in,
                              void* d_out, int out_size, void* d_ws, size_t ws_size,
                              hipStream_t stream)
{
    const float* h     = (const float*)d_in[0];
    const int*   ei    = (const int*)d_in[1];
    const float* Wfc   = (const float*)d_in[2];
    const float* Wattn = (const float*)d_in[3];
    float* out = (float*)d_out;

    int BN = in_sizes[0] / INF;     // B*N = 100000
    int N  = BN / 2;                // 50000
    int E  = in_sizes[1] / 2;       // 800000

    // ws: Whb[BN*64] bf16 | rec[E] u2 | s1[BN] | s2[BN] | deg[N] | rowptr[N+1] | cursor[N]
    __hip_bfloat16* Whb = (__hip_bfloat16*)d_ws;
    uint2*  rec    = (uint2*)(Whb + (size_t)BN * OUTF);
    float*  s1     = (float*)(rec + E);
    float*  s2     = s1 + BN;
    int*    deg    = (int*)(s2 + BN);
    int*    rowptr = deg + N;
    int*    cursor = rowptr + N + 1;

    int nfc   = (BN / 16 + 3) / 4;        // 1563
    int nhist = (E + 255) / 256;          // 3125
    // role map: i%3==0 -> fc (fcid=i/3); i%3==1 -> hist 2k; i%3==2 -> hist 2k+1
    int lastFc   = 3 * (nfc - 1);
    int lastHist = 3 * ((nhist - 1) / 2) + 1 + ((nhist - 1) & 1);
    int grid = (lastFc > lastHist ? lastFc : lastHist) + 1;

    int nscan = (N + 2047) / 2048;        // 25 for N=50000

    hipMemsetAsync(deg, 0, (size_t)N * sizeof(int), stream);

    k_fc_hist<<<grid, 256, 0, stream>>>(h, Wfc, Wattn, Whb, s1, s2,
                                        ei + E, deg, BN, N, E, nhist);
    k_scan<<<nscan, 256, 0, stream>>>(deg, rowptr, cursor, N, E);
    k_scatter<<<(E + 255) / 256, 256, 0, stream>>>(ei, ei + E, s1, s2, cursor, rec, E, N);
    k_gather<<<(N + 3) / 4, 256, 0, stream>>>(rowptr, rec, (const unsigned int*)Whb, out, N);
}

// Round 2
// 210.622 us; speedup vs baseline: 1.0554x; 1.0554x over previous
//
#include <hip/hip_runtime.h>
#include <hip/hip_bf16.h>

#define INF 128
#define OUTF 64
#define ALPHA 0.2f
#define EPSV 1e-6f

typedef __bf16 bf16x8 __attribute__((ext_vector_type(8)));
typedef float  f32x4  __attribute__((ext_vector_type(4)));

// ---------------------------------------------------------------------------
// k_fc_hist (fat kernel): blockIdx%3==0 -> FC role (MFMA), else -> histogram.
//
// FC role (R2 rework): weights staged in LDS as pre-split bf16 hi/lo
// fragments, loaded cooperatively ONCE per block. The K-loop ds_reads each
// fragment just-in-time -> no 128-VGPR live weight array -> no scratch spill
// (R1's 60us / 39MB WRITE_SIZE / everything-idle signature).
//
// LDS layout (bf16x8 units): f = ((kb*4 + t)*4 + quad)*16 + q
//   holds W[t*16+q][kb*32 + quad*8 + j], j=0..7.
// Read pattern per (kb,t): lanes (quad,q) -> contiguous 1KB -> conflict-free.
//
// Whb stored interleaved [n][b][64] bf16 (256B/node).
// s1/s2 interleaved [n][b] (float2/node) for 8B scatter gathers.
// ---------------------------------------------------------------------------
__global__ __launch_bounds__(256, 4)
void k_fc_hist(const float* __restrict__ h, const float* __restrict__ Wfc,
               const float* __restrict__ Wattn, __hip_bfloat16* __restrict__ Whb,
               float* __restrict__ s1, float* __restrict__ s2,
               const int* __restrict__ e_dst, int* __restrict__ deg,
               int BN, int N, int E, int nhist)
{
    int blk = blockIdx.x;
    int k = blk / 3;
    int r = blk - 3 * k;

    if (r != 0) {
        // ---- histogram role ----
        int histid = 2 * k + (r - 1);
        if (histid < nhist) {
            int e = histid * 256 + threadIdx.x;
            if (e < E) {
                int d = e_dst[e];
                d = min(max(d, 0), N - 1);
                atomicAdd(deg + d, 1);
            }
        }
        return;
    }

    // ---- FC role (fcid = k) ----
    __shared__ bf16x8 s_whi[1024];   // 16 KB
    __shared__ bf16x8 s_wlo[1024];   // 16 KB

    int tid  = threadIdx.x;
    int lane = tid & 63;
    int wv   = k * 4 + (tid >> 6);
    int base = wv * 16;
    int q = lane & 15, quad = lane >> 4;

    // Cooperative weight load+split: thread tid owns row (tid>>2),
    // cols (tid&3)*32 .. +31  ->  kb = tid&3, quad(c8) = 0..3, t = row>>4.
    {
        int row = tid >> 2;
        int kb  = tid & 3;
        int t   = row >> 4;
        int qq  = row & 15;
        const float* wp = Wfc + (size_t)row * INF + kb * 32;
#pragma unroll
        for (int c8 = 0; c8 < 4; ++c8) {
            float4 w0 = *(const float4*)(wp + c8 * 8);
            float4 w1 = *(const float4*)(wp + c8 * 8 + 4);
            float wv8[8] = {w0.x, w0.y, w0.z, w0.w, w1.x, w1.y, w1.z, w1.w};
            bf16x8 hi8, lo8;
#pragma unroll
            for (int j = 0; j < 8; ++j) {
                hi8[j] = (__bf16)wv8[j];
                lo8[j] = (__bf16)(wv8[j] - (float)hi8[j]);
            }
            int f = ((kb * 4 + t) * 4 + c8) * 16 + qq;
            s_whi[f] = hi8;
            s_wlo[f] = lo8;
        }
    }
    __syncthreads();

    if (base >= BN) return;

    f32x4 acc[4];
#pragma unroll
    for (int t = 0; t < 4; ++t) acc[t] = (f32x4){0.f, 0.f, 0.f, 0.f};

    const float* hrow = h + (size_t)(base + q) * INF + quad * 8;
#pragma unroll
    for (int kb = 0; kb < 4; ++kb) {
        float4 h0 = *(const float4*)(hrow + kb * 32);
        float4 h1 = *(const float4*)(hrow + kb * 32 + 4);
        float hv8[8] = {h0.x, h0.y, h0.z, h0.w, h1.x, h1.y, h1.z, h1.w};
        bf16x8 ahi, alo;
#pragma unroll
        for (int j = 0; j < 8; ++j) {
            ahi[j] = (__bf16)hv8[j];
            alo[j] = (__bf16)(hv8[j] - (float)ahi[j]);
        }
#pragma unroll
        for (int t = 0; t < 4; ++t) {
            int f = ((kb * 4 + t) * 4 + quad) * 16 + q;
            bf16x8 wh = s_whi[f];
            bf16x8 wl = s_wlo[f];
            acc[t] = __builtin_amdgcn_mfma_f32_16x16x32_bf16(ahi, wh, acc[t], 0, 0, 0);
            acc[t] = __builtin_amdgcn_mfma_f32_16x16x32_bf16(ahi, wl, acc[t], 0, 0, 0);
            acc[t] = __builtin_amdgcn_mfma_f32_16x16x32_bf16(alo, wh, acc[t], 0, 0, 0);
        }
    }

#pragma unroll
    for (int rr4 = 0; rr4 < 4; ++rr4) {
        int rr = base + quad * 4 + rr4;
        int b = (rr >= N) ? 1 : 0;
        int n = rr - b * N;
        __hip_bfloat16* dst = Whb + (size_t)n * 128 + b * 64 + q;
#pragma unroll
        for (int t = 0; t < 4; ++t) dst[t * 16] = __float2bfloat16(acc[t][rr4]);
    }

    float aS[4], aD[4];
#pragma unroll
    for (int t = 0; t < 4; ++t) {
        aS[t] = Wattn[t * 16 + q];
        aD[t] = Wattn[OUTF + t * 16 + q];
    }
    float t1[4], t2[4];
#pragma unroll
    for (int rr4 = 0; rr4 < 4; ++rr4) {
        t1[rr4] = acc[0][rr4] * aS[0] + acc[1][rr4] * aS[1] + acc[2][rr4] * aS[2] + acc[3][rr4] * aS[3];
        t2[rr4] = acc[0][rr4] * aD[0] + acc[1][rr4] * aD[1] + acc[2][rr4] * aD[2] + acc[3][rr4] * aD[3];
    }
#pragma unroll
    for (int off = 1; off <= 8; off <<= 1) {
#pragma unroll
        for (int rr4 = 0; rr4 < 4; ++rr4) {
            t1[rr4] += __shfl_xor(t1[rr4], off, 64);
            t2[rr4] += __shfl_xor(t2[rr4], off, 64);
        }
    }
    if (q == 0) {
#pragma unroll
        for (int rr4 = 0; rr4 < 4; ++rr4) {
            int rr = base + quad * 4 + rr4;
            int b = (rr >= N) ? 1 : 0;
            int n = rr - b * N;
            s1[2 * n + b] = t1[rr4];   // interleaved [n][b]
            s2[2 * n + b] = t2[rr4];
        }
    }
}

// ---------------------------------------------------------------------------
// k_scan: each block redundantly computes its exclusive prefix from deg
// (L2-resident, 200KB), scans its 2048 elements, writes rowptr AND cursor.
// ---------------------------------------------------------------------------
__global__ __launch_bounds__(256)
void k_scan(const int* __restrict__ deg, int* __restrict__ rowptr,
            int* __restrict__ cursor, int N, int E)
{
    int t = threadIdx.x, lane = t & 63, wave = t >> 6;
    __shared__ int pre_ws[4];
    __shared__ int wsum[4];

    int myStart = blockIdx.x * 2048;
    int s = 0;
    for (int i0 = t * 8; i0 < myStart; i0 += 2048) {
        int4 v0 = *(const int4*)(deg + i0);
        int4 v1 = *(const int4*)(deg + i0 + 4);
        s += v0.x + v0.y + v0.z + v0.w + v1.x + v1.y + v1.z + v1.w;
    }
#pragma unroll
    for (int off = 32; off >= 1; off >>= 1) s += __shfl_xor(s, off, 64);
    if (lane == 0) pre_ws[wave] = s;
    __syncthreads();
    int pre = pre_ws[0] + pre_ws[1] + pre_ws[2] + pre_ws[3];

    int base = myStart + t * 8;
    int vals[8]; int sl = 0;
#pragma unroll
    for (int j = 0; j < 8; ++j) {
        int i = base + j;
        vals[j] = (i < N) ? deg[i] : 0;
        sl += vals[j];
    }
    int inc = sl;
#pragma unroll
    for (int off = 1; off < 64; off <<= 1) {
        int u = __shfl_up(inc, off, 64);
        if (lane >= off) inc += u;
    }
    if (lane == 63) wsum[wave] = inc;
    __syncthreads();

    int woff = 0;
#pragma unroll
    for (int w = 0; w < 4; ++w) if (w < wave) woff += wsum[w];
    int running = pre + woff + (inc - sl);
#pragma unroll
    for (int j = 0; j < 8; ++j) {
        int i = base + j;
        if (i < N) { rowptr[i] = running; cursor[i] = running; }
        running += vals[j];
    }
    if (blockIdx.x == 0 && t == 0) rowptr[N] = E;
}

// ---------------------------------------------------------------------------
// Scatter: slot via atomicAdd on cursor. s1/s2 interleaved [n][b]: one
// float2 gather per endpoint. One 8B record per edge.
// ---------------------------------------------------------------------------
__global__ __launch_bounds__(256)
void k_scatter(const int* __restrict__ e_src, const int* __restrict__ e_dst,
               const float* __restrict__ s1, const float* __restrict__ s2,
               int* __restrict__ cursor, uint2* __restrict__ rec, int E, int N)
{
    int e = blockIdx.x * 256 + threadIdx.x;
    if (e >= E) return;
    int d = e_dst[e];
    int s = e_src[e];
    d = min(max(d, 0), N - 1);
    s = min(max(s, 0), N - 1);
    int p = atomicAdd(cursor + d, 1);
    float2 vs = ((const float2*)s1)[s];
    float2 vd = ((const float2*)s2)[d];
    float e0 = vs.x + vd.x;
    float e1 = vs.y + vd.y;
    e0 = e0 > 0.f ? e0 : ALPHA * e0;
    e1 = e1 > 0.f ? e1 : ALPHA * e1;
    float x0 = __expf(e0);
    float x1 = __expf(e1);
    __hip_bfloat16 b0 = __float2bfloat16(x0);
    __hip_bfloat16 b1 = __float2bfloat16(x1);
    unsigned u0 = *(unsigned short*)&b0;
    unsigned u1 = *(unsigned short*)&b1;
    rec[p] = make_uint2((unsigned)s, u0 | (u1 << 16));
}

// ---------------------------------------------------------------------------
// k_gather: one wave per dst. Lane = (g = edge slot 0..3, q = 0..15):
// q<8 -> batch0, q>=8 -> batch1. 8 edges/iter; reduce over g via shfl_xor.
// ---------------------------------------------------------------------------
__global__ __launch_bounds__(256)
void k_gather(const int* __restrict__ rowptr, const uint2* __restrict__ rec,
              const unsigned int* __restrict__ Whb, float* __restrict__ out, int N)
{
    int lane = threadIdx.x & 63;
    int d = blockIdx.x * 4 + (threadIdx.x >> 6);
    if (d >= N) return;
    int g = lane >> 4, q = lane & 15;
    int b = q >> 3;

    int beg = rowptr[d];
    int end = rowptr[d + 1];
    const uint4* W = (const uint4*)Whb;

    float a[8];
#pragma unroll
    for (int j = 0; j < 8; ++j) a[j] = 0.f;
    float nacc = 0.f;

    for (int i = beg; i < end; i += 8) {
        int e0 = i + g;
        int e1 = i + 4 + g;
        int ec0 = min(e0, end - 1);
        int ec1 = min(e1, end - 1);
        uint2 r0 = rec[ec0];
        uint2 r1 = rec[ec1];
        int s0 = (int)r0.x;
        int s1v = (int)r1.x;
        uint4 w0 = W[(size_t)s0 * 16 + q];
        uint4 w1 = W[(size_t)s1v * 16 + q];
        float x0 = (e0 < end) ? __uint_as_float(b ? (r0.y & 0xffff0000u) : (r0.y << 16)) : 0.f;
        float x1 = (e1 < end) ? __uint_as_float(b ? (r1.y & 0xffff0000u) : (r1.y << 16)) : 0.f;

        unsigned int u;
        u = w0.x; a[0] += x0 * __uint_as_float(u << 16); a[1] += x0 * __uint_as_float(u & 0xffff0000u);
        u = w0.y; a[2] += x0 * __uint_as_float(u << 16); a[3] += x0 * __uint_as_float(u & 0xffff0000u);
        u = w0.z; a[4] += x0 * __uint_as_float(u << 16); a[5] += x0 * __uint_as_float(u & 0xffff0000u);
        u = w0.w; a[6] += x0 * __uint_as_float(u << 16); a[7] += x0 * __uint_as_float(u & 0xffff0000u);
        u = w1.x; a[0] += x1 * __uint_as_float(u << 16); a[1] += x1 * __uint_as_float(u & 0xffff0000u);
        u = w1.y; a[2] += x1 * __uint_as_float(u << 16); a[3] += x1 * __uint_as_float(u & 0xffff0000u);
        u = w1.z; a[4] += x1 * __uint_as_float(u << 16); a[5] += x1 * __uint_as_float(u & 0xffff0000u);
        u = w1.w; a[6] += x1 * __uint_as_float(u << 16); a[7] += x1 * __uint_as_float(u & 0xffff0000u);
        nacc += x0 + x1;
    }

#pragma unroll
    for (int off = 16; off <= 32; off <<= 1) {
#pragma unroll
        for (int j = 0; j < 8; ++j) a[j] += __shfl_xor(a[j], off, 64);
        nacc += __shfl_xor(nacc, off, 64);
    }

    if (g == 0) {
        float inv = 1.f / (nacc + EPSV);
        float v[8];
#pragma unroll
        for (int j = 0; j < 8; ++j) {
            v[j] = a[j] * inv;
            v[j] = v[j] > 0.f ? v[j] : expm1f(v[j]);
        }
        size_t rowbase = ((size_t)b * N + d) * 16 + (size_t)(q & 7) * 2;
        ((float4*)out)[rowbase]     = make_float4(v[0], v[1], v[2], v[3]);
        ((float4*)out)[rowbase + 1] = make_float4(v[4], v[5], v[6], v[7]);
    }
}

extern "C" void kernel_launch(void* const* d_in, const int* in_sizes, int n_in,
                              void* d_out, int out_size, void* d_ws, size_t ws_size,
                              hipStream_t stream)
{
    const float* h     = (const float*)d_in[0];
    const int*   ei    = (const int*)d_in[1];
    const float* Wfc   = (const float*)d_in[2];
    const float* Wattn = (const float*)d_in[3];
    float* out = (float*)d_out;

    int BN = in_sizes[0] / INF;     // B*N = 100000
    int N  = BN / 2;                // 50000
    int E  = in_sizes[1] / 2;       // 800000

    // ws: Whb[BN*64] bf16 | rec[E] u2 | s1[BN] | s2[BN] | deg[N] | rowptr[N+1] | cursor[N]
    __hip_bfloat16* Whb = (__hip_bfloat16*)d_ws;
    uint2*  rec    = (uint2*)(Whb + (size_t)BN * OUTF);
    float*  s1     = (float*)(rec + E);
    float*  s2     = s1 + BN;
    int*    deg    = (int*)(s2 + BN);
    int*    rowptr = deg + N;
    int*    cursor = rowptr + N + 1;

    int nfc   = (BN / 16 + 3) / 4;        // 1563
    int nhist = (E + 255) / 256;          // 3125
    int lastFc   = 3 * (nfc - 1);
    int lastHist = 3 * ((nhist - 1) / 2) + 1 + ((nhist - 1) & 1);
    int grid = (lastFc > lastHist ? lastFc : lastHist) + 1;

    int nscan = (N + 2047) / 2048;        // 25 for N=50000

    hipMemsetAsync(deg, 0, (size_t)N * sizeof(int), stream);

    k_fc_hist<<<grid, 256, 0, stream>>>(h, Wfc, Wattn, Whb, s1, s2,
                                        ei + E, deg, BN, N, E, nhist);
    k_scan<<<nscan, 256, 0, stream>>>(deg, rowptr, cursor, N, E);
    k_scatter<<<(E + 255) / 256, 256, 0, stream>>>(ei, ei + E, s1, s2, cursor, rec, E, N);
    k_gather<<<(N + 3) / 4, 256, 0, stream>>>(rowptr, rec, (const unsigned int*)Whb, out, N);
}

// Round 3
// 188.368 us; speedup vs baseline: 1.1801x; 1.1181x over previous
//
#include <hip/hip_runtime.h>
#include <hip/hip_bf16.h>

#define INF 128
#define OUTF 64
#define ALPHA 0.2f
#define EPSV 1e-6f

typedef __bf16 bf16x8 __attribute__((ext_vector_type(8)));
typedef float  f32x4  __attribute__((ext_vector_type(4)));

// ---------------------------------------------------------------------------
// k_fc_hist (fat kernel): 5-slot interleave, blk%5==4 -> histogram role
// (8 edges/thread, rank capture), else FC role (MFMA with LDS-staged weights).
//
// Hist role: int4x2 coalesced dst loads, 8 independent atomics in flight,
// atomic return stored as rank[e] (kills the second atomic pass in scatter).
//
// FC role: h prefetched to registers BEFORE weight staging (HBM latency
// hides under convert+sync). Weights pre-split bf16 hi/lo in 32KB LDS.
// Whb stored interleaved [n][b][64] bf16; s1/s2 interleaved [n][b] float2.
// ---------------------------------------------------------------------------
__global__ __launch_bounds__(256, 4)
void k_fc_hist(const float* __restrict__ h, const float* __restrict__ Wfc,
               const float* __restrict__ Wattn, __hip_bfloat16* __restrict__ Whb,
               float* __restrict__ s1, float* __restrict__ s2,
               const int* __restrict__ e_dst, int* __restrict__ deg,
               int* __restrict__ rank, int BN, int N, int E)
{
    int blk = blockIdx.x;
    int g5 = blk / 5;
    int r5 = blk - 5 * g5;

    if (r5 == 4) {
        // ---- histogram role: 2048 edges per virtual block ----
        int base_e = g5 * 2048 + threadIdx.x * 8;
        if (base_e < E) {
            if (base_e + 8 <= E) {
                int4 d0 = *(const int4*)(e_dst + base_e);
                int4 d1 = *(const int4*)(e_dst + base_e + 4);
                int dd[8] = {d0.x, d0.y, d0.z, d0.w, d1.x, d1.y, d1.z, d1.w};
                int rk[8];
#pragma unroll
                for (int j = 0; j < 8; ++j) {
                    int d = min(max(dd[j], 0), N - 1);
                    rk[j] = atomicAdd(deg + d, 1);
                }
                *(int4*)(rank + base_e)     = make_int4(rk[0], rk[1], rk[2], rk[3]);
                *(int4*)(rank + base_e + 4) = make_int4(rk[4], rk[5], rk[6], rk[7]);
            } else {
                for (int j = 0; j < 8 && base_e + j < E; ++j) {
                    int d = e_dst[base_e + j];
                    d = min(max(d, 0), N - 1);
                    rank[base_e + j] = atomicAdd(deg + d, 1);
                }
            }
        }
        return;
    }

    // ---- FC role ----
    int fcid = g5 * 4 + r5;
    __shared__ bf16x8 s_whi[1024];   // 16 KB
    __shared__ bf16x8 s_wlo[1024];   // 16 KB

    int tid  = threadIdx.x;
    int lane = tid & 63;
    int wv   = fcid * 4 + (tid >> 6);
    int base = wv * 16;
    int q = lane & 15, quad = lane >> 4;

    // Prefetch this wave's h fragment (clamped row for OOB waves).
    int hr = min(base + q, BN - 1);
    const float* hrow = h + (size_t)hr * INF + quad * 8;
    float4 hp[8];
#pragma unroll
    for (int kb = 0; kb < 4; ++kb) {
        hp[2 * kb]     = *(const float4*)(hrow + kb * 32);
        hp[2 * kb + 1] = *(const float4*)(hrow + kb * 32 + 4);
    }

    // Cooperative weight load+split (once per block).
    {
        int row = tid >> 2;
        int kb  = tid & 3;
        int t   = row >> 4;
        int qq  = row & 15;
        const float* wp = Wfc + (size_t)row * INF + kb * 32;
#pragma unroll
        for (int c8 = 0; c8 < 4; ++c8) {
            float4 w0 = *(const float4*)(wp + c8 * 8);
            float4 w1 = *(const float4*)(wp + c8 * 8 + 4);
            float wv8[8] = {w0.x, w0.y, w0.z, w0.w, w1.x, w1.y, w1.z, w1.w};
            bf16x8 hi8, lo8;
#pragma unroll
            for (int j = 0; j < 8; ++j) {
                hi8[j] = (__bf16)wv8[j];
                lo8[j] = (__bf16)(wv8[j] - (float)hi8[j]);
            }
            int f = ((kb * 4 + t) * 4 + c8) * 16 + qq;
            s_whi[f] = hi8;
            s_wlo[f] = lo8;
        }
    }
    __syncthreads();

    if (base >= BN) return;

    f32x4 acc[4];
#pragma unroll
    for (int t = 0; t < 4; ++t) acc[t] = (f32x4){0.f, 0.f, 0.f, 0.f};

#pragma unroll
    for (int kb = 0; kb < 4; ++kb) {
        float4 h0 = hp[2 * kb];
        float4 h1 = hp[2 * kb + 1];
        float hv8[8] = {h0.x, h0.y, h0.z, h0.w, h1.x, h1.y, h1.z, h1.w};
        bf16x8 ahi, alo;
#pragma unroll
        for (int j = 0; j < 8; ++j) {
            ahi[j] = (__bf16)hv8[j];
            alo[j] = (__bf16)(hv8[j] - (float)ahi[j]);
        }
#pragma unroll
        for (int t = 0; t < 4; ++t) {
            int f = ((kb * 4 + t) * 4 + quad) * 16 + q;
            bf16x8 wh = s_whi[f];
            bf16x8 wl = s_wlo[f];
            acc[t] = __builtin_amdgcn_mfma_f32_16x16x32_bf16(ahi, wh, acc[t], 0, 0, 0);
            acc[t] = __builtin_amdgcn_mfma_f32_16x16x32_bf16(ahi, wl, acc[t], 0, 0, 0);
            acc[t] = __builtin_amdgcn_mfma_f32_16x16x32_bf16(alo, wh, acc[t], 0, 0, 0);
        }
    }

#pragma unroll
    for (int rr4 = 0; rr4 < 4; ++rr4) {
        int rr = base + quad * 4 + rr4;
        int b = (rr >= N) ? 1 : 0;
        int n = rr - b * N;
        __hip_bfloat16* dst = Whb + (size_t)n * 128 + b * 64 + q;
#pragma unroll
        for (int t = 0; t < 4; ++t) dst[t * 16] = __float2bfloat16(acc[t][rr4]);
    }

    float aS[4], aD[4];
#pragma unroll
    for (int t = 0; t < 4; ++t) {
        aS[t] = Wattn[t * 16 + q];
        aD[t] = Wattn[OUTF + t * 16 + q];
    }
    float t1[4], t2[4];
#pragma unroll
    for (int rr4 = 0; rr4 < 4; ++rr4) {
        t1[rr4] = acc[0][rr4] * aS[0] + acc[1][rr4] * aS[1] + acc[2][rr4] * aS[2] + acc[3][rr4] * aS[3];
        t2[rr4] = acc[0][rr4] * aD[0] + acc[1][rr4] * aD[1] + acc[2][rr4] * aD[2] + acc[3][rr4] * aD[3];
    }
#pragma unroll
    for (int off = 1; off <= 8; off <<= 1) {
#pragma unroll
        for (int rr4 = 0; rr4 < 4; ++rr4) {
            t1[rr4] += __shfl_xor(t1[rr4], off, 64);
            t2[rr4] += __shfl_xor(t2[rr4], off, 64);
        }
    }
    if (q == 0) {
#pragma unroll
        for (int rr4 = 0; rr4 < 4; ++rr4) {
            int rr = base + quad * 4 + rr4;
            int b = (rr >= N) ? 1 : 0;
            int n = rr - b * N;
            s1[2 * n + b] = t1[rr4];
            s2[2 * n + b] = t2[rr4];
        }
    }
}

// ---------------------------------------------------------------------------
// k_scan: each block redundantly computes its exclusive prefix from deg
// (L2-resident, 200KB), scans its 2048 elements, writes rowptr.
// ---------------------------------------------------------------------------
__global__ __launch_bounds__(256)
void k_scan(const int* __restrict__ deg, int* __restrict__ rowptr, int N, int E)
{
    int t = threadIdx.x, lane = t & 63, wave = t >> 6;
    __shared__ int pre_ws[4];
    __shared__ int wsum[4];

    int myStart = blockIdx.x * 2048;
    int s = 0;
    for (int i0 = t * 8; i0 < myStart; i0 += 2048) {
        int4 v0 = *(const int4*)(deg + i0);
        int4 v1 = *(const int4*)(deg + i0 + 4);
        s += v0.x + v0.y + v0.z + v0.w + v1.x + v1.y + v1.z + v1.w;
    }
#pragma unroll
    for (int off = 32; off >= 1; off >>= 1) s += __shfl_xor(s, off, 64);
    if (lane == 0) pre_ws[wave] = s;
    __syncthreads();
    int pre = pre_ws[0] + pre_ws[1] + pre_ws[2] + pre_ws[3];

    int base = myStart + t * 8;
    int vals[8]; int sl = 0;
#pragma unroll
    for (int j = 0; j < 8; ++j) {
        int i = base + j;
        vals[j] = (i < N) ? deg[i] : 0;
        sl += vals[j];
    }
    int inc = sl;
#pragma unroll
    for (int off = 1; off < 64; off <<= 1) {
        int u = __shfl_up(inc, off, 64);
        if (lane >= off) inc += u;
    }
    if (lane == 63) wsum[wave] = inc;
    __syncthreads();

    int woff = 0;
#pragma unroll
    for (int w = 0; w < 4; ++w) if (w < wave) woff += wsum[w];
    int running = pre + woff + (inc - sl);
#pragma unroll
    for (int j = 0; j < 8; ++j) {
        int i = base + j;
        if (i < N) rowptr[i] = running;
        running += vals[j];
    }
    if (blockIdx.x == 0 && t == 0) rowptr[N] = E;
}

// ---------------------------------------------------------------------------
// Scatter (atomic-free, batched): 4 edges/thread, coalesced int4 loads of
// src/dst/rank, p = rowptr[d] + rank[e]. 4 independent gather chains.
// One 8B record per edge: (src:u32, x0:bf16 | x1:bf16<<16).
// ---------------------------------------------------------------------------
__global__ __launch_bounds__(256)
void k_scatter(const int* __restrict__ e_src, const int* __restrict__ e_dst,
               const float* __restrict__ s1, const float* __restrict__ s2,
               const int* __restrict__ rowptr, const int* __restrict__ rank,
               uint2* __restrict__ rec, int E, int N)
{
    int base_e = (blockIdx.x * 256 + threadIdx.x) * 4;
    if (base_e >= E) return;
    if (base_e + 4 <= E) {
        int4 s4 = *(const int4*)(e_src + base_e);
        int4 d4 = *(const int4*)(e_dst + base_e);
        int4 r4 = *(const int4*)(rank + base_e);
        int ss[4] = {s4.x, s4.y, s4.z, s4.w};
        int dd[4] = {d4.x, d4.y, d4.z, d4.w};
        int rk[4] = {r4.x, r4.y, r4.z, r4.w};
#pragma unroll
        for (int j = 0; j < 4; ++j) {
            int d = min(max(dd[j], 0), N - 1);
            int s = min(max(ss[j], 0), N - 1);
            int p = rowptr[d] + rk[j];
            float2 vs = ((const float2*)s1)[s];
            float2 vd = ((const float2*)s2)[d];
            float e0 = vs.x + vd.x;
            float e1 = vs.y + vd.y;
            e0 = e0 > 0.f ? e0 : ALPHA * e0;
            e1 = e1 > 0.f ? e1 : ALPHA * e1;
            float x0 = __expf(e0);
            float x1 = __expf(e1);
            __hip_bfloat16 b0 = __float2bfloat16(x0);
            __hip_bfloat16 b1 = __float2bfloat16(x1);
            unsigned u0 = *(unsigned short*)&b0;
            unsigned u1 = *(unsigned short*)&b1;
            rec[p] = make_uint2((unsigned)s, u0 | (u1 << 16));
        }
    } else {
        for (int j = 0; j < 4 && base_e + j < E; ++j) {
            int e = base_e + j;
            int d = min(max(e_dst[e], 0), N - 1);
            int s = min(max(e_src[e], 0), N - 1);
            int p = rowptr[d] + rank[e];
            float2 vs = ((const float2*)s1)[s];
            float2 vd = ((const float2*)s2)[d];
            float e0 = vs.x + vd.x;
            float e1 = vs.y + vd.y;
            e0 = e0 > 0.f ? e0 : ALPHA * e0;
            e1 = e1 > 0.f ? e1 : ALPHA * e1;
            float x0 = __expf(e0);
            float x1 = __expf(e1);
            __hip_bfloat16 b0 = __float2bfloat16(x0);
            __hip_bfloat16 b1 = __float2bfloat16(x1);
            unsigned u0 = *(unsigned short*)&b0;
            unsigned u1 = *(unsigned short*)&b1;
            rec[p] = make_uint2((unsigned)s, u0 | (u1 << 16));
        }
    }
}

// ---------------------------------------------------------------------------
// k_gather: one wave per dst, 16 edges per iteration (4 independent 256B
// W-row chains per lane -> 4-deep MLP against L3 latency). Lane = (g,q):
// g = edge slot group 0..3, q = 0..15 (q<8 batch0, q>=8 batch1).
// ---------------------------------------------------------------------------
__global__ __launch_bounds__(256)
void k_gather(const int* __restrict__ rowptr, const uint2* __restrict__ rec,
              const unsigned int* __restrict__ Whb, float* __restrict__ out, int N)
{
    int lane = threadIdx.x & 63;
    int d = blockIdx.x * 4 + (threadIdx.x >> 6);
    if (d >= N) return;
    int g = lane >> 4, q = lane & 15;
    int b = q >> 3;

    int beg = rowptr[d];
    int end = rowptr[d + 1];
    const uint4* W = (const uint4*)Whb;

    float a[8];
#pragma unroll
    for (int j = 0; j < 8; ++j) a[j] = 0.f;
    float nacc = 0.f;

    for (int i = beg; i < end; i += 16) {
        int e[4], ec[4];
        uint2 r[4];
#pragma unroll
        for (int k = 0; k < 4; ++k) {
            e[k] = i + 4 * k + g;
            ec[k] = min(e[k], end - 1);
            r[k] = rec[ec[k]];
        }
        uint4 w[4];
#pragma unroll
        for (int k = 0; k < 4; ++k) w[k] = W[(size_t)(int)r[k].x * 16 + q];
        float x[4];
#pragma unroll
        for (int k = 0; k < 4; ++k) {
            x[k] = (e[k] < end) ? __uint_as_float(b ? (r[k].y & 0xffff0000u) : (r[k].y << 16)) : 0.f;
            nacc += x[k];
        }
#pragma unroll
        for (int k = 0; k < 4; ++k) {
            unsigned int u;
            u = w[k].x; a[0] += x[k] * __uint_as_float(u << 16); a[1] += x[k] * __uint_as_float(u & 0xffff0000u);
            u = w[k].y; a[2] += x[k] * __uint_as_float(u << 16); a[3] += x[k] * __uint_as_float(u & 0xffff0000u);
            u = w[k].z; a[4] += x[k] * __uint_as_float(u << 16); a[5] += x[k] * __uint_as_float(u & 0xffff0000u);
            u = w[k].w; a[6] += x[k] * __uint_as_float(u << 16); a[7] += x[k] * __uint_as_float(u & 0xffff0000u);
        }
    }

#pragma unroll
    for (int off = 16; off <= 32; off <<= 1) {
#pragma unroll
        for (int j = 0; j < 8; ++j) a[j] += __shfl_xor(a[j], off, 64);
        nacc += __shfl_xor(nacc, off, 64);
    }

    if (g == 0) {
        float inv = 1.f / (nacc + EPSV);
        float v[8];
#pragma unroll
        for (int j = 0; j < 8; ++j) {
            v[j] = a[j] * inv;
            v[j] = v[j] > 0.f ? v[j] : expm1f(v[j]);
        }
        size_t rowbase = ((size_t)b * N + d) * 16 + (size_t)(q & 7) * 2;
        ((float4*)out)[rowbase]     = make_float4(v[0], v[1], v[2], v[3]);
        ((float4*)out)[rowbase + 1] = make_float4(v[4], v[5], v[6], v[7]);
    }
}

extern "C" void kernel_launch(void* const* d_in, const int* in_sizes, int n_in,
                              void* d_out, int out_size, void* d_ws, size_t ws_size,
                              hipStream_t stream)
{
    const float* h     = (const float*)d_in[0];
    const int*   ei    = (const int*)d_in[1];
    const float* Wfc   = (const float*)d_in[2];
    const float* Wattn = (const float*)d_in[3];
    float* out = (float*)d_out;

    int BN = in_sizes[0] / INF;     // B*N = 100000
    int N  = BN / 2;                // 50000
    int E  = in_sizes[1] / 2;       // 800000

    // ws: Whb[BN*64] bf16 | rec[E] u2 | s1[BN] | s2[BN] | deg[N] | rowptr[N+1] | rank[E]
    __hip_bfloat16* Whb = (__hip_bfloat16*)d_ws;
    uint2*  rec    = (uint2*)(Whb + (size_t)BN * OUTF);
    float*  s1     = (float*)(rec + E);
    float*  s2     = s1 + BN;
    int*    deg    = (int*)(s2 + BN);
    int*    rowptr = deg + N;
    int*    rank   = rowptr + N + 1;

    int nfc    = (BN / 16 + 3) / 4;          // 1563 fc virtual blocks
    int nhistB = (E + 2047) / 2048;          // 391 hist virtual blocks
    int gridA  = 5 * ((nfc + 3) / 4);        // fc needs 4 slots per group of 5
    int gridB  = 5 * nhistB;
    int grid   = gridA > gridB ? gridA : gridB;

    int nscan = (N + 2047) / 2048;           // 25 for N=50000

    hipMemsetAsync(deg, 0, (size_t)N * sizeof(int), stream);

    k_fc_hist<<<grid, 256, 0, stream>>>(h, Wfc, Wattn, Whb, s1, s2,
                                        ei + E, deg, rank, BN, N, E);
    k_scan<<<nscan, 256, 0, stream>>>(deg, rowptr, N, E);
    k_scatter<<<((E + 3) / 4 + 255) / 256, 256, 0, stream>>>(ei, ei + E, s1, s2,
                                                             rowptr, rank, rec, E, N);
    k_gather<<<(N + 3) / 4, 256, 0, stream>>>(rowptr, rec, (const unsigned int*)Whb, out, N);
}